// Round 2
// baseline (319.952 us; speedup 1.0000x reference)
//
#include <hip/hip_runtime.h>
#include <hip/hip_bf16.h>

#define NN   4096
#define BB   4
#define CIN_ 128
#define CKEY_ 64
#define COUT_ 128

typedef __attribute__((ext_vector_type(8))) short bf16x8;
typedef __attribute__((ext_vector_type(4))) float f32x4;

__device__ __forceinline__ float bf2f(short s) {
    unsigned int u = ((unsigned int)(unsigned short)s) << 16;
    union { unsigned int u; float f; } c; c.u = u; return c.f;
}
__device__ __forceinline__ short f2bf(float f) {
    union { float f; unsigned int u; } c; c.f = f;
    unsigned int r = c.u + 0x7fffu + ((c.u >> 16) & 1u);  // RNE
    return (short)(r >> 16);
}

// ---------------- Kernel 0: W (fp32, [k][i]) -> Wt fp32 [i][256] ----------------
__global__ __launch_bounds__(256) void wcvt_kernel(const float* __restrict__ Wq,
                                                   const float* __restrict__ Wk,
                                                   const float* __restrict__ Wv,
                                                   float* __restrict__ Wt) {
    int id = blockIdx.x * 256 + threadIdx.x;      // 32768 total
    int i  = id & 127;                            // lanes -> consecutive i (coalesced reads)
    int kk = id >> 7;                             // 0..255
    float v;
    if (kk < 64)        v = Wq[kk * CIN_ + i];
    else if (kk < 128)  v = Wk[(kk - 64) * CIN_ + i];
    else                v = Wv[(kk - 128) * CIN_ + i];
    Wt[i * 256 + kk] = v;
}

// ---------------- Kernel 1: projections ----------------
// grid (N/64, B), block 256. wave grp: 0=Q, 1=K, 2=V[0:64), 3=V[64:128)
// Qh/Ql/Kh/Kl layout: [b][chunk 0..7][n][8] bf16 (chunk c covers dims c*8..c*8+7)
// V layout: [b][o][n] bf16
__global__ __launch_bounds__(256) void proj_kernel(const float* __restrict__ x,
                                                   const float* __restrict__ Wt,
                                                   short* __restrict__ Qh, short* __restrict__ Ql,
                                                   short* __restrict__ Kh, short* __restrict__ Kl,
                                                   short* __restrict__ Vb) {
    int tid = threadIdx.x;
    int b   = blockIdx.y;
    int n   = blockIdx.x * 64 + (tid & 63);
    int grp = __builtin_amdgcn_readfirstlane(tid >> 6);   // wave-uniform -> scalar W loads

    float acc[64];
#pragma unroll
    for (int g = 0; g < 64; ++g) acc[g] = 0.f;

    const float* wbase = Wt + grp * 64;
#pragma unroll 4
    for (int i = 0; i < CIN_; ++i) {
        float xv = x[(b * CIN_ + i) * NN + n];
        const float* wr = wbase + i * 256;
#pragma unroll
        for (int g = 0; g < 64; ++g) acc[g] = fmaf(wr[g], xv, acc[g]);
    }

    if (grp < 2) {
        short* H = grp ? Kh : Qh;
        short* L = grp ? Kl : Ql;
#pragma unroll
        for (int qc = 0; qc < 8; ++qc) {
            bf16x8 h8, l8;
#pragma unroll
            for (int j = 0; j < 8; ++j) {
                float f = acc[qc * 8 + j];
                short h = f2bf(f);
                float res = f - bf2f(h);
                h8[j] = h;
                l8[j] = f2bf(res);
            }
            int off = (((b * 8 + qc) * NN) + n) * 8;
            *(bf16x8*)(H + off) = h8;
            *(bf16x8*)(L + off) = l8;
        }
    } else {
        int o0 = (grp - 2) * 64;
#pragma unroll
        for (int g = 0; g < 64; ++g) {
            Vb[((b * COUT_) + o0 + g) * NN + n] = f2bf(acc[g]);
        }
    }
}

// ---------------- Kernel 2: flash attention ----------------
// grid (N/64, B), block 256 (4 waves). Wave w owns queries [qt*64 + w*16, +16).
// Per iteration: stage 32 keys (Kh,Kl rows padded to 72 elems) + V[128][32] (rows padded to 40).
#define MFMA16 __builtin_amdgcn_mfma_f32_16x16x32_bf16

__global__ __launch_bounds__(256) void flash_kernel(const short* __restrict__ Qh,
                                                    const short* __restrict__ Ql,
                                                    const short* __restrict__ Kh,
                                                    const short* __restrict__ Kl,
                                                    const short* __restrict__ Vb,
                                                    float* __restrict__ out) {
    constexpr int KSTR = 72;   // 64 + 8 pad (144 B rows, 16B-aligned, 2-way banks max)
    constexpr int VSTR = 40;   // 32 + 8 pad (80 B rows)
    __shared__ __align__(16) short KhT[32 * KSTR];
    __shared__ __align__(16) short KlT[32 * KSTR];
    __shared__ __align__(16) short VT[128 * VSTR];
    __shared__ __align__(16) short PT[4 * 16 * VSTR];   // per-wave P scratch

    int tid  = threadIdx.x;
    int b    = blockIdx.y;
    int wave = tid >> 6;
    int lane = tid & 63;
    int quad = lane >> 4;
    int l15  = lane & 15;

    // A-fragments of Q for this wave's 16 rows (dims chunk0 = quad, chunk1 = 4+quad)
    int nq = blockIdx.x * 64 + wave * 16 + l15;
    bf16x8 qh0 = *(const bf16x8*)(Qh + (((b * 8 + quad)     * NN) + nq) * 8);
    bf16x8 qh1 = *(const bf16x8*)(Qh + (((b * 8 + 4 + quad) * NN) + nq) * 8);
    bf16x8 ql0 = *(const bf16x8*)(Ql + (((b * 8 + quad)     * NN) + nq) * 8);
    bf16x8 ql1 = *(const bf16x8*)(Ql + (((b * 8 + 4 + quad) * NN) + nq) * 8);

    f32x4 O[8];
#pragma unroll
    for (int f = 0; f < 8; ++f) O[f] = (f32x4){0.f, 0.f, 0.f, 0.f};
    float m_i[4], l_i[4];
#pragma unroll
    for (int r = 0; r < 4; ++r) { m_i[r] = -3.0e38f; l_i[r] = 0.f; }

    int krow = tid & 31, kcc = tid >> 5;   // K staging: 32 rows x 8 dim-chunks
    int vcc  = tid & 3,  vrow = tid >> 2;  // V staging: 128 rows x 4 m-chunks (2 rows/thread)
    const float LOG2E = 1.4426950408889634f;

    for (int kc = 0; kc < NN / 32; ++kc) {
        int m0 = kc * 32;
        *(bf16x8*)(KhT + krow * KSTR + kcc * 8) =
            *(const bf16x8*)(Kh + (((b * 8 + kcc) * NN) + m0 + krow) * 8);
        *(bf16x8*)(KlT + krow * KSTR + kcc * 8) =
            *(const bf16x8*)(Kl + (((b * 8 + kcc) * NN) + m0 + krow) * 8);
        *(bf16x8*)(VT + vrow * VSTR + vcc * 8) =
            *(const bf16x8*)(Vb + (b * COUT_ + vrow) * NN + m0 + vcc * 8);
        *(bf16x8*)(VT + (vrow + 64) * VSTR + vcc * 8) =
            *(const bf16x8*)(Vb + (b * COUT_ + vrow + 64) * NN + m0 + vcc * 8);
        __syncthreads();

        // S = Qh*Kh + Qh*Kl + Ql*Kh  over 64-dim contraction (two 32-chunks)
        f32x4 s0 = (f32x4){0.f, 0.f, 0.f, 0.f};
        f32x4 s1 = (f32x4){0.f, 0.f, 0.f, 0.f};
        {
            const short* rh0 = KhT + l15 * KSTR + quad * 8;
            const short* rl0 = KlT + l15 * KSTR + quad * 8;
            bf16x8 bh0 = *(const bf16x8*)(rh0);
            bf16x8 bh1 = *(const bf16x8*)(rh0 + 32);
            bf16x8 bl0 = *(const bf16x8*)(rl0);
            bf16x8 bl1 = *(const bf16x8*)(rl0 + 32);
            s0 = MFMA16(qh0, bh0, s0, 0, 0, 0);
            s0 = MFMA16(qh1, bh1, s0, 0, 0, 0);
            s0 = MFMA16(qh0, bl0, s0, 0, 0, 0);
            s0 = MFMA16(qh1, bl1, s0, 0, 0, 0);
            s0 = MFMA16(ql0, bh0, s0, 0, 0, 0);
            s0 = MFMA16(ql1, bh1, s0, 0, 0, 0);
        }
        {
            const short* rh1 = KhT + (16 + l15) * KSTR + quad * 8;
            const short* rl1 = KlT + (16 + l15) * KSTR + quad * 8;
            bf16x8 ch0 = *(const bf16x8*)(rh1);
            bf16x8 ch1 = *(const bf16x8*)(rh1 + 32);
            bf16x8 cl0 = *(const bf16x8*)(rl1);
            bf16x8 cl1 = *(const bf16x8*)(rl1 + 32);
            s1 = MFMA16(qh0, ch0, s1, 0, 0, 0);
            s1 = MFMA16(qh1, ch1, s1, 0, 0, 0);
            s1 = MFMA16(qh0, cl0, s1, 0, 0, 0);
            s1 = MFMA16(qh1, cl1, s1, 0, 0, 0);
            s1 = MFMA16(ql0, ch0, s1, 0, 0, 0);
            s1 = MFMA16(ql1, ch1, s1, 0, 0, 0);
        }

        // online softmax (rows = quad*4 + r, cols spread over 16 lanes of the quad)
        float p0[4], p1[4], alpha[4];
#pragma unroll
        for (int r = 0; r < 4; ++r) {
            float vm = fmaxf(s0[r], s1[r]);
            vm = fmaxf(vm, __shfl_xor(vm, 8, 16));
            vm = fmaxf(vm, __shfl_xor(vm, 4, 16));
            vm = fmaxf(vm, __shfl_xor(vm, 2, 16));
            vm = fmaxf(vm, __shfl_xor(vm, 1, 16));
            float nm = fmaxf(m_i[r], vm);
            alpha[r] = exp2f((m_i[r] - nm) * LOG2E);
            p0[r]    = exp2f((s0[r] - nm) * LOG2E);
            p1[r]    = exp2f((s1[r] - nm) * LOG2E);
            m_i[r]   = nm;
            float rs = p0[r] + p1[r];
            rs += __shfl_xor(rs, 8, 16);
            rs += __shfl_xor(rs, 4, 16);
            rs += __shfl_xor(rs, 2, 16);
            rs += __shfl_xor(rs, 1, 16);
            l_i[r] = l_i[r] * alpha[r] + rs;
        }
#pragma unroll
        for (int f = 0; f < 8; ++f) {
#pragma unroll
            for (int r = 0; r < 4; ++r) O[f][r] *= alpha[r];
        }

        // P (C/D layout) -> LDS -> A-operand layout
        short* pw = PT + wave * 16 * VSTR;
#pragma unroll
        for (int r = 0; r < 4; ++r) {
            pw[(quad * 4 + r) * VSTR + l15]      = f2bf(p0[r]);
            pw[(quad * 4 + r) * VSTR + 16 + l15] = f2bf(p1[r]);
        }
        bf16x8 pA = *(const bf16x8*)(pw + l15 * VSTR + quad * 8);

#pragma unroll
        for (int oc = 0; oc < 8; ++oc) {
            bf16x8 vB = *(const bf16x8*)(VT + (oc * 16 + l15) * VSTR + quad * 8);
            O[oc] = MFMA16(pA, vB, O[oc], 0, 0, 0);
        }
        __syncthreads();
    }

    // epilogue: divide by l, store fp32 [b][o][n], 4 consecutive n per lane
    float rl[4];
#pragma unroll
    for (int r = 0; r < 4; ++r) rl[r] = 1.f / l_i[r];
    int n_out = blockIdx.x * 64 + wave * 16 + quad * 4;
#pragma unroll
    for (int oc = 0; oc < 8; ++oc) {
        int o = oc * 16 + l15;
        f32x4 ov;
#pragma unroll
        for (int r = 0; r < 4; ++r) ov[r] = O[oc][r] * rl[r];
        *(f32x4*)(out + (b * COUT_ + o) * NN + n_out) = ov;
    }
}

extern "C" void kernel_launch(void* const* d_in, const int* in_sizes, int n_in,
                              void* d_out, int out_size, void* d_ws, size_t ws_size,
                              hipStream_t stream) {
    const float* x  = (const float*)d_in[0];
    const float* Wq = (const float*)d_in[1];
    const float* Wk = (const float*)d_in[2];
    const float* Wv = (const float*)d_in[3];

    char* ws = (char*)d_ws;
    float* Wt = (float*)ws;                          // 128*256*4 = 131072 B
    short* Qh = (short*)(ws + 131072);               // 4*8*4096*8 shorts = 2 MB
    short* Ql = Qh + 1048576;
    short* Kh = Ql + 1048576;
    short* Kl = Kh + 1048576;
    short* Vb = Kl + 1048576;                        // 4*128*4096 shorts = 4 MB
    // total ws use: ~12.1 MB

    wcvt_kernel<<<128, 256, 0, stream>>>(Wq, Wk, Wv, Wt);
    proj_kernel<<<dim3(NN / 64, BB), 256, 0, stream>>>(x, Wt, Qh, Ql, Kh, Kl, Vb);
    flash_kernel<<<dim3(NN / 64, BB), 256, 0, stream>>>(Qh, Ql, Kh, Kl, Vb, (float*)d_out);
}

// Round 4
// 167.967 us; speedup vs baseline: 1.9049x; 1.9049x over previous
//
#include <hip/hip_runtime.h>
#include <hip/hip_bf16.h>

#define NN    4096
#define BB    4
#define CIN_  128
#define CKEY_ 64
#define COUT_ 128

typedef __attribute__((ext_vector_type(8))) short bf16x8;
typedef __attribute__((ext_vector_type(4))) float f32x4;

#define MFMA16 __builtin_amdgcn_mfma_f32_16x16x32_bf16

__device__ __forceinline__ float bf2f(short s) {
    union { unsigned int u; float f; } c; c.u = ((unsigned int)(unsigned short)s) << 16; return c.f;
}
__device__ __forceinline__ short f2bf(float f) {
    union { float f; unsigned int u; } c; c.f = f;
    unsigned int r = c.u + 0x7fffu + ((c.u >> 16) & 1u);  // RNE
    return (short)(r >> 16);
}
__device__ __forceinline__ float fexp2(float x) {
#if __has_builtin(__builtin_amdgcn_exp2f)
    return __builtin_amdgcn_exp2f(x);
#else
    return exp2f(x);
#endif
}
// word = bf16(a) | bf16(b)<<16 (round-half-up)
__device__ __forceinline__ unsigned int pack_bf16(float a, float b) {
    union { float f; unsigned int u; } ca, cb; ca.f = a; cb.f = b;
    unsigned int ua = ca.u + 0x8000u, ub = cb.u + 0x8000u;
#if __has_builtin(__builtin_amdgcn_perm)
    return __builtin_amdgcn_perm(ub, ua, 0x07060302u);   // lo<-ua.hi16, hi<-ub.hi16
#else
    return (ua >> 16) | (ub & 0xffff0000u);
#endif
}

// ---------------- Kernel 0: W (fp32, [k][i]) -> Wt fp32 [i][256] ----------------
__global__ __launch_bounds__(256) void wcvt_kernel(const float* __restrict__ Wq,
                                                   const float* __restrict__ Wk,
                                                   const float* __restrict__ Wv,
                                                   float* __restrict__ Wt) {
    int id = blockIdx.x * 256 + threadIdx.x;      // 32768 total
    int i  = id & 127;
    int kk = id >> 7;
    float v;
    if (kk < 64)        v = Wq[kk * CIN_ + i];
    else if (kk < 128)  v = Wk[(kk - 64) * CIN_ + i];
    else                v = Wv[(kk - 128) * CIN_ + i];
    Wt[i * 256 + kk] = v;
}

// ---------------- Kernel 1: projections ----------------
// grid (N/64, B, 4). z: 0=Q 1=K 2=V[0:64) 3=V[64:128). Wave w -> outs [w*16,w*16+16).
// Q pre-scaled by log2(e). Qh/Ql/Kh/Kl layout: [b][chunk0..7][n][8] bf16. V: [b][o][n] bf16.
__global__ __launch_bounds__(256, 4) void proj_kernel(const float* __restrict__ x,
                                                      const float* __restrict__ Wt,
                                                      short* __restrict__ Qh, short* __restrict__ Ql,
                                                      short* __restrict__ Kh, short* __restrict__ Kl,
                                                      short* __restrict__ Vb) {
    __shared__ float Ws[CIN_ * 64];
    int tid  = threadIdx.x;
    int b    = blockIdx.y;
    int gz   = blockIdx.z;
    int n    = blockIdx.x * 64 + (tid & 63);
    int wave = tid >> 6;

    const float* wsrc = Wt + gz * 64;
#pragma unroll
    for (int r = 0; r < 8; ++r) {
        int flat = r * 256 + tid;            // over 2048 float4s
        int i = flat >> 4, c4 = (flat & 15) * 4;
        *(f32x4*)&Ws[i * 64 + c4] = *(const f32x4*)(wsrc + i * 256 + c4);
    }
    __syncthreads();

    float acc[16];
#pragma unroll
    for (int g = 0; g < 16; ++g) acc[g] = 0.f;

    const float* xcol = x + (size_t)b * CIN_ * NN + n;
    int wo = wave * 16;
#pragma unroll 4
    for (int i = 0; i < CIN_; ++i) {
        float xv = xcol[i * NN];
        const float* wr = Ws + i * 64 + wo;
#pragma unroll
        for (int c4 = 0; c4 < 4; ++c4) {
            f32x4 wv = *(const f32x4*)(wr + c4 * 4);
#pragma unroll
            for (int j = 0; j < 4; ++j) acc[c4 * 4 + j] = fmaf(wv[j], xv, acc[c4 * 4 + j]);
        }
    }

    if (gz < 2) {
        if (gz == 0) {
            const float LOG2E = 1.4426950408889634f;
#pragma unroll
            for (int g = 0; g < 16; ++g) acc[g] *= LOG2E;
        }
        short* H = gz ? Kh : Qh;
        short* L = gz ? Kl : Ql;
#pragma unroll
        for (int cc = 0; cc < 2; ++cc) {
            bf16x8 h8, l8;
#pragma unroll
            for (int j = 0; j < 8; ++j) {
                float f = acc[cc * 8 + j];
                short h = f2bf(f);
                h8[j] = h;
                l8[j] = f2bf(f - bf2f(h));
            }
            int off = (((b * 8 + wave * 2 + cc) * NN) + n) * 8;
            *(bf16x8*)(H + off) = h8;
            *(bf16x8*)(L + off) = l8;
        }
    } else {
        int o0 = (gz - 2) * 64 + wo;
#pragma unroll
        for (int g = 0; g < 16; ++g)
            Vb[((b * COUT_) + o0 + g) * NN + n] = f2bf(acc[g]);
    }
}

// ---------------- Kernel 2: flash attention (S^T scheme) ----------------
// grid (N/64, B, S), block 256. Wave w: queries qt*64+w*16..+16 (query = lane&15).
// S^T = K·Q^T (keys = C/D rows, queries = cols): per-lane scalar m/l/alpha.
// P -> PV B-operand: shuffle BOTH candidate f-blocks, select post-shuffle by dest fsel.
__global__ __launch_bounds__(256, 4) void flash_kernel(const short* __restrict__ Qh,
                                                       const short* __restrict__ Ql,
                                                       const short* __restrict__ Kh,
                                                       const short* __restrict__ Kl,
                                                       const short* __restrict__ Vb,
                                                       float* __restrict__ outp,
                                                       float* __restrict__ ml,
                                                       int S, int direct) {
    constexpr int KSTR = 72;   // 64 + 8 pad shorts (144 B rows)
    __shared__ __align__(16) short KhT[64 * KSTR];
    __shared__ __align__(16) short KlT[64 * KSTR];
    __shared__ __align__(16) short VT[128 * KSTR];

    int tid  = threadIdx.x;
    int b    = blockIdx.y;
    int s    = blockIdx.z;
    int wave = tid >> 6;
    int lane = tid & 63;
    int quad = lane >> 4;
    int l15  = lane & 15;

    // Q B-operand frags (query = l15), dim chunks quad and 4+quad
    int nq = blockIdx.x * 64 + wave * 16 + l15;
    bf16x8 qh0 = *(const bf16x8*)(Qh + (((b * 8 + quad)     * NN) + nq) * 8);
    bf16x8 qh1 = *(const bf16x8*)(Qh + (((b * 8 + 4 + quad) * NN) + nq) * 8);
    bf16x8 ql0 = *(const bf16x8*)(Ql + (((b * 8 + quad)     * NN) + nq) * 8);
    bf16x8 ql1 = *(const bf16x8*)(Ql + (((b * 8 + 4 + quad) * NN) + nq) * 8);

    f32x4 O[8];
#pragma unroll
    for (int f = 0; f < 8; ++f) O[f] = (f32x4){0.f, 0.f, 0.f, 0.f};
    float m_i = -1.0e30f, l_i = 0.f;

    int krow = tid & 63, kc2 = (tid >> 6) * 2;          // K: 64 rows x chunks {kc2,kc2+1}
    int vrow = tid & 127, vg = (tid >> 7) * 32;         // V: 128 rows x 32-col half
    int sl0 = (quad & 1) * 32 + l15;                    // source lanes for P permute
    int sl1 = sl0 + 16;
    int fsel = quad >> 1;                               // dest-side f-block select

    int KPS  = NN / S;
    int kb   = s * KPS;
    int iters = KPS / 64;

    const short* KhB = Kh + (size_t)b * 8 * NN * 8;
    const short* KlB = Kl + (size_t)b * 8 * NN * 8;
    const short* VbB = Vb + (size_t)b * COUT_ * NN;

    for (int it = 0; it < iters; ++it, kb += 64) {
        // ---- stage K (hi+lo) and V tiles ----
#pragma unroll
        for (int cc = 0; cc < 2; ++cc) {
            int c = kc2 + cc;
            *(bf16x8*)(KhT + krow * KSTR + c * 8) = *(const bf16x8*)(KhB + ((c * NN) + kb + krow) * 8);
            *(bf16x8*)(KlT + krow * KSTR + c * 8) = *(const bf16x8*)(KlB + ((c * NN) + kb + krow) * 8);
        }
#pragma unroll
        for (int q = 0; q < 4; ++q) {
            *(bf16x8*)(VT + vrow * KSTR + vg + q * 8) =
                *(const bf16x8*)(VbB + (size_t)vrow * NN + kb + vg + q * 8);
        }
        __syncthreads();

        // ---- S^T = Kh·Qh + Kl·Qh + Kh·Ql ----
        f32x4 sA[4];
#pragma unroll
        for (int f = 0; f < 4; ++f) {
            const short* rh = KhT + (f * 16 + l15) * KSTR + quad * 8;
            const short* rl = KlT + (f * 16 + l15) * KSTR + quad * 8;
            bf16x8 kh0 = *(const bf16x8*)(rh);
            bf16x8 kh1 = *(const bf16x8*)(rh + 32);
            bf16x8 kl0 = *(const bf16x8*)(rl);
            bf16x8 kl1 = *(const bf16x8*)(rl + 32);
            f32x4 acc = (f32x4){0.f, 0.f, 0.f, 0.f};
            acc = MFMA16(kh0, qh0, acc, 0, 0, 0);
            acc = MFMA16(kh1, qh1, acc, 0, 0, 0);
            acc = MFMA16(kl0, qh0, acc, 0, 0, 0);
            acc = MFMA16(kl1, qh1, acc, 0, 0, 0);
            acc = MFMA16(kh0, ql0, acc, 0, 0, 0);
            acc = MFMA16(kh1, ql1, acc, 0, 0, 0);
            sA[f] = acc;
        }

        // ---- online softmax, per-lane scalar state (query = l15) ----
        float vm = sA[0][0];
#pragma unroll
        for (int f = 0; f < 4; ++f)
#pragma unroll
            for (int r = 0; r < 4; ++r) vm = fmaxf(vm, sA[f][r]);
        vm = fmaxf(vm, __shfl_xor(vm, 16, 64));
        vm = fmaxf(vm, __shfl_xor(vm, 32, 64));
        float nm    = fmaxf(m_i, vm);
        float alpha = fexp2(m_i - nm);
        m_i = nm;

        float p[4][4];
        float rs = 0.f;
#pragma unroll
        for (int f = 0; f < 4; ++f)
#pragma unroll
            for (int r = 0; r < 4; ++r) {
                float pv = fexp2(sA[f][r] - nm);
                p[f][r] = pv;
                rs += pv;
            }
        rs += __shfl_xor(rs, 16, 64);
        rs += __shfl_xor(rs, 32, 64);
        l_i = l_i * alpha + rs;

        if (__any(alpha < 1.0f)) {
#pragma unroll
            for (int f = 0; f < 8; ++f)
#pragma unroll
                for (int r = 0; r < 4; ++r) O[f][r] *= alpha;
        }

        // ---- pack P, permute to PV B-operand (post-shuffle select), PV MFMAs ----
        unsigned int w[4][2];
#pragma unroll
        for (int f = 0; f < 4; ++f) {
            w[f][0] = pack_bf16(p[f][0], p[f][1]);
            w[f][1] = pack_bf16(p[f][2], p[f][3]);
        }
#pragma unroll
        for (int g = 0; g < 2; ++g) {
            int a0 = __shfl((int)w[g * 2][0],     sl0, 64);
            int a1 = __shfl((int)w[g * 2][1],     sl0, 64);
            int a2 = __shfl((int)w[g * 2][0],     sl1, 64);
            int a3 = __shfl((int)w[g * 2][1],     sl1, 64);
            int b0 = __shfl((int)w[g * 2 + 1][0], sl0, 64);
            int b1 = __shfl((int)w[g * 2 + 1][1], sl0, 64);
            int b2 = __shfl((int)w[g * 2 + 1][0], sl1, 64);
            int b3 = __shfl((int)w[g * 2 + 1][1], sl1, 64);
            union { int i[4]; bf16x8 v; } pb;
            pb.i[0] = fsel ? b0 : a0;
            pb.i[1] = fsel ? b1 : a1;
            pb.i[2] = fsel ? b2 : a2;
            pb.i[3] = fsel ? b3 : a3;
#pragma unroll
            for (int f8 = 0; f8 < 8; ++f8) {
                bf16x8 vA = *(const bf16x8*)(VT + (f8 * 16 + l15) * KSTR + g * 32 + quad * 8);
                O[f8] = MFMA16(vA, pb.v, O[f8], 0, 0, 0);
            }
        }
        __syncthreads();
    }

    // ---- epilogue: O^T per-lane column (query = l15), rows o = f8*16+quad*4+r ----
    int n = blockIdx.x * 64 + wave * 16 + l15;
    if (direct) {
        float inv = 1.f / l_i;
#pragma unroll
        for (int f8 = 0; f8 < 8; ++f8) {
#pragma unroll
            for (int r = 0; r < 4; ++r) {
                int o = f8 * 16 + quad * 4 + r;
                outp[((size_t)(b * COUT_ + o)) * NN + n] = O[f8][r] * inv;
            }
        }
    } else {
#pragma unroll
        for (int f8 = 0; f8 < 8; ++f8) {
#pragma unroll
            for (int r = 0; r < 4; ++r) {
                int o = f8 * 16 + quad * 4 + r;
                outp[((size_t)((b * S + s) * COUT_ + o)) * NN + n] = O[f8][r];
            }
        }
        if (quad == 0) {
            ml[((b * S + s) * 2 + 0) * NN + n] = m_i;
            ml[((b * S + s) * 2 + 1) * NN + n] = l_i;
        }
    }
}

// ---------------- Kernel 3: merge K-split partials ----------------
__global__ __launch_bounds__(256, 4) void merge_kernel(const float* __restrict__ Opart,
                                                       const float* __restrict__ ml,
                                                       float* __restrict__ out, int S) {
    int idx = blockIdx.x * 256 + threadIdx.x;   // over B*COUT*N/4
    int n0  = (idx & (NN / 4 - 1)) * 4;
    int rest = idx >> 10;
    int o = rest & (COUT_ - 1);
    int b = rest >> 7;

    f32x4 gm = (f32x4){-1.0e30f, -1.0e30f, -1.0e30f, -1.0e30f};
    for (int s = 0; s < S; ++s) {
        f32x4 m = *(const f32x4*)(ml + ((b * S + s) * 2 + 0) * NN + n0);
#pragma unroll
        for (int j = 0; j < 4; ++j) gm[j] = fmaxf(gm[j], m[j]);
    }
    f32x4 acc = (f32x4){0.f, 0.f, 0.f, 0.f};
    f32x4 den = (f32x4){0.f, 0.f, 0.f, 0.f};
    for (int s = 0; s < S; ++s) {
        f32x4 m = *(const f32x4*)(ml + ((b * S + s) * 2 + 0) * NN + n0);
        f32x4 l = *(const f32x4*)(ml + ((b * S + s) * 2 + 1) * NN + n0);
        f32x4 ov = *(const f32x4*)(Opart + ((size_t)((b * S + s) * COUT_ + o)) * NN + n0);
#pragma unroll
        for (int j = 0; j < 4; ++j) {
            float ws = fexp2(m[j] - gm[j]);
            acc[j] = fmaf(ws, ov[j], acc[j]);
            den[j] = fmaf(ws, l[j], den[j]);
        }
    }
    f32x4 res;
#pragma unroll
    for (int j = 0; j < 4; ++j) res[j] = acc[j] / den[j];
    *(f32x4*)(out + ((size_t)(b * COUT_ + o)) * NN + n0) = res;
}

extern "C" void kernel_launch(void* const* d_in, const int* in_sizes, int n_in,
                              void* d_out, int out_size, void* d_ws, size_t ws_size,
                              hipStream_t stream) {
    const float* x  = (const float*)d_in[0];
    const float* Wq = (const float*)d_in[1];
    const float* Wk = (const float*)d_in[2];
    const float* Wv = (const float*)d_in[3];

    char* ws = (char*)d_ws;
    float* Wt = (float*)ws;                          // 131072 B
    short* Qh = (short*)(ws + 131072);               // 4 x 2 MB
    short* Ql = Qh + 1048576;
    short* Kh = Ql + 1048576;
    short* Kl = Kh + 1048576;
    short* Vb = Kl + 1048576;                        // 4 MB
    size_t base = 131072 + 4ull * 2097152 + 4194304; // 12.7 MB
    const size_t OPART = 8388608;                    // B*COUT*N*4 per split
    const size_t MLSZ  = 131072;                     // B*2*N*4 per split

    int S;
    if      (ws_size >= base + 4 * (OPART + MLSZ)) S = 4;
    else if (ws_size >= base + 2 * (OPART + MLSZ)) S = 2;
    else                                           S = 1;
    int direct = (S == 1);

    float* mlp   = (float*)(ws + base);
    float* Opart = (float*)(ws + base + (size_t)S * MLSZ);

    wcvt_kernel<<<128, 256, 0, stream>>>(Wq, Wk, Wv, Wt);
    proj_kernel<<<dim3(NN / 64, BB, 4), 256, 0, stream>>>(x, Wt, Qh, Ql, Kh, Kl, Vb);
    flash_kernel<<<dim3(NN / 64, BB, S), 256, 0, stream>>>(
        Qh, Ql, Kh, Kl, Vb, direct ? (float*)d_out : Opart, mlp, S, direct);
    if (!direct)
        merge_kernel<<<BB * COUT_ * NN / 4 / 256, 256, 0, stream>>>(Opart, mlp, (float*)d_out, S);
}